// Round 2
// baseline (415.570 us; speedup 1.0000x reference)
//
#include <hip/hip_runtime.h>

// ---------------------------------------------------------------------------
// TabularDiffFlow sparse-attention pipeline, MI355X (gfx950)
// B=64, N=256, D=512, H=8, HD=64, top-k = 128 of 256 per score row.
//
// Precision plan: q,k projections and QK^T in split-bf16 (hi+lo, 3 MFMAs)
// so top-k boundary decisions match the fp32 reference; v/P/out-proj plain bf16.
//
// R1: attn restructured — no K/V LDS staging (L1/L2-resident), V pre-transposed
// into MFMA fragment layout by the v-GEMM epilogue, pe loaded as float4
// fragments, grid 2048 blocks (1 q-tile/wave) with XCD swizzle.
// ---------------------------------------------------------------------------

typedef __attribute__((ext_vector_type(8))) short short8;
typedef __attribute__((ext_vector_type(4))) float float4v;

#define MFMA16(A,B,C) __builtin_amdgcn_mfma_f32_16x16x32_bf16((A),(B),(C),0,0,0)

__device__ __forceinline__ ushort f2bf(float f){
  unsigned u = __float_as_uint(f);
  unsigned r = u + 0x7FFFu + ((u >> 16) & 1u);   // round-to-nearest-even
  return (ushort)(r >> 16);
}
__device__ __forceinline__ float bf2f(ushort h){
  return __uint_as_float(((unsigned)h) << 16);
}
// inverse of the "sortable uint" map (monotone uint <-> float bits)
__device__ __forceinline__ float unsort_u(unsigned u){
  unsigned b = (u & 0x80000000u) ? (u ^ 0x80000000u) : ~u;
  return __uint_as_float(b);
}

// ---------------------------------------------------------------- cvt_x ----
__global__ __launch_bounds__(256) void cvt_x_k(const float* __restrict__ x,
                                               ushort* __restrict__ xhi,
                                               ushort* __restrict__ xlo){
  size_t i = ((size_t)blockIdx.x * 256 + threadIdx.x) * 8;
  float4v a = *(const float4v*)(x + i);
  float4v b = *(const float4v*)(x + i + 4);
  float v0=a[0],v1=a[1],v2=a[2],v3=a[3],v4=b[0],v5=b[1],v6=b[2],v7=b[3];
  ushort h0=f2bf(v0),h1=f2bf(v1),h2=f2bf(v2),h3=f2bf(v3);
  ushort h4=f2bf(v4),h5=f2bf(v5),h6=f2bf(v6),h7=f2bf(v7);
  ushort l0=f2bf(v0-bf2f(h0)),l1=f2bf(v1-bf2f(h1)),l2=f2bf(v2-bf2f(h2)),l3=f2bf(v3-bf2f(h3));
  ushort l4=f2bf(v4-bf2f(h4)),l5=f2bf(v5-bf2f(h5)),l6=f2bf(v6-bf2f(h6)),l7=f2bf(v7-bf2f(h7));
  uint4 ph, pl;
  ph.x = h0 | ((unsigned)h1<<16); ph.y = h2 | ((unsigned)h3<<16);
  ph.z = h4 | ((unsigned)h5<<16); ph.w = h6 | ((unsigned)h7<<16);
  pl.x = l0 | ((unsigned)l1<<16); pl.y = l2 | ((unsigned)l3<<16);
  pl.z = l4 | ((unsigned)l5<<16); pl.w = l6 | ((unsigned)l7<<16);
  *(uint4*)(xhi + i) = ph;
  *(uint4*)(xlo + i) = pl;
}

// ---------------------------------------------------------------- cvt_w ----
__global__ __launch_bounds__(256) void cvt_w_k(
    const float* __restrict__ Wq, const float* __restrict__ Wk,
    const float* __restrict__ Wv, const float* __restrict__ Wo,
    const float* __restrict__ bq, const float* __restrict__ bk, const float* __restrict__ bv,
    ushort* __restrict__ Wthi, ushort* __restrict__ Wtlo, ushort* __restrict__ Wot,
    float* __restrict__ fb){
  int r = blockIdx.x, t = threadIdx.x;
  if (r < 1536) {
    const float* W = (r < 512) ? Wq : ((r < 1024) ? Wk : Wv);
    int o = r & 511;
    bool dolo = (r < 1024);
    for (int i = t; i < 512; i += 256) {
      float f = W[(size_t)i*512 + o];
      ushort hi = f2bf(f);
      Wthi[(size_t)r*512 + i] = hi;
      if (dolo) Wtlo[(size_t)r*512 + i] = f2bf(f - bf2f(hi));
    }
  } else if (r < 2048) {
    int o = r - 1536;
    for (int i = t; i < 512; i += 256)
      Wot[(size_t)o*512 + i] = f2bf(Wo[(size_t)i*512 + o]);
  } else {
    for (int i = t; i < 1536; i += 256)
      fb[i] = (i < 512) ? bq[i] : ((i < 1024) ? bk[i-512] : bv[i-1024]);
  }
}

// ------------------------------------------------------------ prior_eff ----
__global__ __launch_bounds__(256) void prior_k(const float* __restrict__ prior,
    const float* __restrict__ fimp, float* __restrict__ pe){
  int i = blockIdx.x, j = threadIdx.x;
  pe[(size_t)i*256 + j] = prior[(size_t)i*256 + j] * fimp[i] * fimp[j];
}

// -------------------------------------------------------------- pv path ----
__global__ __launch_bounds__(256) void pv_mean_k(const float* __restrict__ x,
                                                 float* __restrict__ comb){
  int b = blockIdx.x, t = threadIdx.x;
  const float* xb = x + (size_t)b * 131072;   // 256*512
  float p0=0.f,p1=0.f,q0=0.f,q1=0.f;
  for (int n = 0; n < 128; n++){ p0 += xb[n*512 + t]; p1 += xb[n*512 + t + 256]; }
  for (int n = 128; n < 256; n++){ q0 += xb[n*512 + t]; q1 += xb[n*512 + t + 256]; }
  const float s = 1.0f/128.0f;
  comb[(size_t)b*1024 + t]         = p0*s;
  comb[(size_t)b*1024 + t + 256]   = p1*s;
  comb[(size_t)b*1024 + 512 + t]       = q0*s;
  comb[(size_t)b*1024 + 512 + t + 256] = q1*s;
}

__global__ __launch_bounds__(256) void pv_mlp_k(const float* __restrict__ comb,
    const float* __restrict__ W1, const float* __restrict__ b1,
    const float* __restrict__ W2, const float* __restrict__ b2,
    float* __restrict__ pvc){
  __shared__ float cs[1024];
  __shared__ float red[256];
  int b = blockIdx.x, t = threadIdx.x;
  for (int i = t; i < 1024; i += 256) cs[i] = comb[(size_t)b*1024 + i];
  __syncthreads();
  float a0 = b1[t], a1 = b1[t + 256];
  for (int i = 0; i < 1024; i++){
    float c = cs[i];
    a0 = fmaf(c, W1[(size_t)i*512 + t],       a0);
    a1 = fmaf(c, W1[(size_t)i*512 + t + 256], a1);
  }
  float h0 = a0 / (1.0f + __expf(-a0));   // silu
  float h1 = a1 / (1.0f + __expf(-a1));
  red[t] = fmaf(h0, W2[t], h1 * W2[t + 256]);
  __syncthreads();
  for (int s = 128; s > 0; s >>= 1){
    if (t < s) red[t] += red[t + s];
    __syncthreads();
  }
  if (t == 0) pvc[b] = 1.0f / (1.0f + __expf(-(red[0] + b2[0])));
}

// ------------------------------------------------ split GEMM for q and k ---
__global__ __launch_bounds__(256) void gemm_qk(
    const ushort* __restrict__ Ahi, const ushort* __restrict__ Alo,
    const ushort* __restrict__ Bhi, const ushort* __restrict__ Blo,
    const float* __restrict__ bias,
    ushort* __restrict__ qhi, ushort* __restrict__ qlo,
    ushort* __restrict__ khi, ushort* __restrict__ klo)
{
  __shared__ __align__(16) ushort As[2][128][40];
  __shared__ __align__(16) ushort Bs[2][128][40];
  int n0 = blockIdx.x * 128, m0 = blockIdx.y * 128;
  int tid = threadIdx.x, lane = tid & 63, w = tid >> 6, wm = w >> 1, wn = w & 1;
  float4v acc[4][4] = {};
  for (int k0 = 0; k0 < 512; k0 += 32){
    for (int c = tid; c < 512; c += 256){
      int row = c >> 2, ch = c & 3;
      *(uint4*)(&As[0][row][ch*8]) = *(const uint4*)(Ahi + (size_t)(m0+row)*512 + k0 + ch*8);
      *(uint4*)(&As[1][row][ch*8]) = *(const uint4*)(Alo + (size_t)(m0+row)*512 + k0 + ch*8);
      *(uint4*)(&Bs[0][row][ch*8]) = *(const uint4*)(Bhi + (size_t)(n0+row)*512 + k0 + ch*8);
      *(uint4*)(&Bs[1][row][ch*8]) = *(const uint4*)(Blo + (size_t)(n0+row)*512 + k0 + ch*8);
    }
    __syncthreads();
    short8 ah[4], al[4], bh[4], bl[4];
    #pragma unroll
    for (int i = 0; i < 4; i++){
      ah[i] = *(const short8*)(&As[0][wm*64 + i*16 + (lane&15)][(lane>>4)*8]);
      al[i] = *(const short8*)(&As[1][wm*64 + i*16 + (lane&15)][(lane>>4)*8]);
      bh[i] = *(const short8*)(&Bs[0][wn*64 + i*16 + (lane&15)][(lane>>4)*8]);
      bl[i] = *(const short8*)(&Bs[1][wn*64 + i*16 + (lane&15)][(lane>>4)*8]);
    }
    #pragma unroll
    for (int mi = 0; mi < 4; mi++){
      #pragma unroll
      for (int ni = 0; ni < 4; ni++){
        acc[mi][ni] = MFMA16(ah[mi], bh[ni], acc[mi][ni]);
        acc[mi][ni] = MFMA16(ah[mi], bl[ni], acc[mi][ni]);
        acc[mi][ni] = MFMA16(al[mi], bh[ni], acc[mi][ni]);
      }
    }
    __syncthreads();
  }
  #pragma unroll
  for (int mi = 0; mi < 4; mi++){
    #pragma unroll
    for (int ni = 0; ni < 4; ni++){
      #pragma unroll
      for (int r = 0; r < 4; r++){
        int rg = m0 + wm*64 + mi*16 + ((lane>>4)<<2) + r;
        int cg = n0 + wn*64 + ni*16 + (lane&15);
        float val = acc[mi][ni][r] + bias[cg];
        int which = cg >> 9, within = cg & 511;
        int bb = rg >> 8, seq = rg & 255, hh = within >> 6, hd = within & 63;
        size_t idx = ((size_t)((bb*8 + hh)*256 + seq))*64 + hd;
        ushort hi_ = f2bf(val);
        ushort lo_ = f2bf(val - bf2f(hi_));
        if (which == 0) { qhi[idx] = hi_; qlo[idx] = lo_; }
        else            { khi[idx] = hi_; klo[idx] = lo_; }
      }
    }
  }
}

// ------------------------------------------- plain bf16 GEMM (v, out-proj) -
// EPI=0: out = bf16 V in MFMA-fragment layout [bh][kb(8)][hd(64)][g*8+j(32)]
//        i.e. element (k=kb*32+wi, hd) of head (b,h) at
//        ((b*8+h)*16384) + (kb*64+hd)*32 + wi.
// EPI=1: out = fp32 [M][512].
template<int EPI>
__global__ __launch_bounds__(256) void gemm_pl(
    const ushort* __restrict__ A, const ushort* __restrict__ Bt,
    const float* __restrict__ bias, void* __restrict__ outp)
{
  __shared__ __align__(16) ushort As[128][40];
  __shared__ __align__(16) ushort Bs[128][40];
  int n0 = blockIdx.x * 128, m0 = blockIdx.y * 128;
  int tid = threadIdx.x, lane = tid & 63, w = tid >> 6, wm = w >> 1, wn = w & 1;
  float4v acc[4][4] = {};
  for (int k0 = 0; k0 < 512; k0 += 32){
    for (int c = tid; c < 512; c += 256){
      int row = c >> 2, ch = c & 3;
      *(uint4*)(&As[row][ch*8]) = *(const uint4*)(A  + (size_t)(m0+row)*512 + k0 + ch*8);
      *(uint4*)(&Bs[row][ch*8]) = *(const uint4*)(Bt + (size_t)(n0+row)*512 + k0 + ch*8);
    }
    __syncthreads();
    short8 af[4], bg[4];
    #pragma unroll
    for (int i = 0; i < 4; i++){
      af[i] = *(const short8*)(&As[wm*64 + i*16 + (lane&15)][(lane>>4)*8]);
      bg[i] = *(const short8*)(&Bs[wn*64 + i*16 + (lane&15)][(lane>>4)*8]);
    }
    #pragma unroll
    for (int mi = 0; mi < 4; mi++){
      #pragma unroll
      for (int ni = 0; ni < 4; ni++)
        acc[mi][ni] = MFMA16(af[mi], bg[ni], acc[mi][ni]);
    }
    __syncthreads();
  }
  #pragma unroll
  for (int mi = 0; mi < 4; mi++){
    #pragma unroll
    for (int ni = 0; ni < 4; ni++){
      int rg0 = m0 + wm*64 + mi*16 + ((lane>>4)<<2);
      int cg  = n0 + wn*64 + ni*16 + (lane&15);
      if (EPI == 0){
        // V fragment layout, 4 consecutive k packed into one 8B store
        int bb = rg0 >> 8, seq0 = rg0 & 255;
        int hh = cg >> 6, hd = cg & 63;
        int kb = seq0 >> 5, wi = seq0 & 31;         // wi multiple of 4
        float b_ = bias[cg];
        uint2 pk;
        pk.x = (unsigned)f2bf(acc[mi][ni][0] + b_) | ((unsigned)f2bf(acc[mi][ni][1] + b_) << 16);
        pk.y = (unsigned)f2bf(acc[mi][ni][2] + b_) | ((unsigned)f2bf(acc[mi][ni][3] + b_) << 16);
        size_t off = ((size_t)(bb*8 + hh) << 14) + (size_t)(((kb<<6) + hd) << 5) + wi;
        *(uint2*)((ushort*)outp + off) = pk;
      } else {
        #pragma unroll
        for (int r = 0; r < 4; r++){
          float val = acc[mi][ni][r] + bias[cg];
          ((float*)outp)[(size_t)(rg0 + r)*512 + cg] = val;
        }
      }
    }
  }
}

// ------------------------------------------------------ fused attention ----
// 2048 blocks (XCD-swizzled), 4 waves each; each wave owns ONE 16-row q tile
// of one (b,h). No K/V LDS staging: K hi/lo fragments read straight from
// global (L1/L2-resident, shared by sibling waves/blocks), V read from the
// pre-transposed fragment layout written by gemm_pl<0>. LDS = per-wave P only.
// Swapped QK^T: mfma(K,Q) => 4-lane group {l,l^16,l^32,l^48} holds the full
// 256-score row of q = lane&15. Exact top-128 via MSB radix-select.
__global__ __launch_bounds__(256) void attn_k(
    const ushort* __restrict__ qhi_, const ushort* __restrict__ qlo_,
    const ushort* __restrict__ khi_, const ushort* __restrict__ klo_,
    const ushort* __restrict__ vt, const float* __restrict__ pe,
    const float* __restrict__ pvc, ushort* __restrict__ ao)
{
  __shared__ __align__(16) ushort Ps[4][16][264];   // per-wave P [q][kpos]

  int blk = (int)((blockIdx.x & 7) * 256 + (blockIdx.x >> 3));  // XCD swizzle (2048%8==0)
  int bh = blk >> 2, quarter = blk & 3;
  int b = bh >> 3, h = bh & 7;
  int tid = threadIdx.x, lane = tid & 63, w = tid >> 6;
  int g = lane >> 4, q15 = lane & 15;
  size_t base = (size_t)bh << 14;          // *16384 elements per (b,h)
  int qbase = quarter*64 + w*16;
  int qg = qbase + q15;
  float pvb = pvc[b] * 0.5f;

  // q fragments (hi+lo)
  const ushort* qp1 = qhi_ + base + (size_t)qg*64 + (g<<3);
  const ushort* qp2 = qlo_ + base + (size_t)qg*64 + (g<<3);
  short8 qh0 = *(const short8*)(qp1);
  short8 qh1 = *(const short8*)(qp1 + 32);
  short8 ql0 = *(const short8*)(qp2);
  short8 ql1 = *(const short8*)(qp2 + 32);

  // QK^T: acc[kt][r] = scores^T[kpos = kt*16+g*4+r][q = q15]
  float4v acc[16];
  #pragma unroll 2
  for (int kt = 0; kt < 16; kt++){
    const ushort* kr1 = khi_ + base + (size_t)((kt<<4) + q15)*64 + (g<<3);
    const ushort* kr2 = klo_ + base + (size_t)((kt<<4) + q15)*64 + (g<<3);
    short8 kh0 = *(const short8*)(kr1);
    short8 kh1 = *(const short8*)(kr1 + 32);
    short8 kl0 = *(const short8*)(kr2);
    short8 kl1 = *(const short8*)(kr2 + 32);
    float4v a = {0.f,0.f,0.f,0.f};
    a = MFMA16(kh0, qh0, a);
    a = MFMA16(kh1, qh1, a);
    a = MFMA16(kh0, ql0, a);
    a = MFMA16(kh1, ql1, a);
    a = MFMA16(kl0, qh0, a);
    a = MFMA16(kl1, qh1, a);
    acc[kt] = a;
  }

  // scale + prior (float4 fragment loads) + price/vol cross-block bias
  bool qlow = (qg < 128);
  #pragma unroll 4
  for (int kt = 0; kt < 16; kt++){
    float4v p4 = *(const float4v*)(pe + qg*256 + (kt<<4) + (g<<2));
    #pragma unroll
    for (int r = 0; r < 4; r++){
      int kpos = (kt<<4) + (g<<2) + r;
      acc[kt][r] = acc[kt][r]*0.125f + p4[r] + ((qlow != (kpos < 128)) ? pvb : 0.0f);
    }
  }

  // exact 128th-largest per row (MSB radix-select on sortable-uint space)
  unsigned thr = 0u; int done = 0;
  for (int bit = 31; bit >= 0; --bit){
    if (__all(done)) break;
    unsigned cand = thr | (1u << bit);
    float tf = unsort_u(cand);
    int cnt = 0;
    #pragma unroll
    for (int kt = 0; kt < 16; kt++){
      #pragma unroll
      for (int r = 0; r < 4; r++)
        cnt += (acc[kt][r] >= tf) ? 1 : 0;
    }
    cnt += __shfl_xor(cnt, 16);
    cnt += __shfl_xor(cnt, 32);
    if (!done && cnt >= 128) thr = cand;
    if (!done && cnt == 128) done = 1;
  }
  float thrf = unsort_u(thr);

  // softmax over kept (row max is always kept)
  float m = -1e30f;
  #pragma unroll
  for (int kt = 0; kt < 16; kt++)
    m = fmaxf(m, fmaxf(fmaxf(acc[kt][0], acc[kt][1]), fmaxf(acc[kt][2], acc[kt][3])));
  m = fmaxf(m, __shfl_xor(m, 16));
  m = fmaxf(m, __shfl_xor(m, 32));
  float sum = 0.0f;
  #pragma unroll
  for (int kt = 0; kt < 16; kt++){
    #pragma unroll
    for (int r = 0; r < 4; r++){
      float e = (acc[kt][r] >= thrf) ? __expf(acc[kt][r] - m) : 0.0f;
      acc[kt][r] = e;
      sum += e;
    }
  }
  sum += __shfl_xor(sum, 16);
  sum += __shfl_xor(sum, 32);
  float inv = 1.0f / sum;

  // normalized P (bf16) -> per-wave LDS: Ps[w][q][kpos]
  #pragma unroll
  for (int kt = 0; kt < 16; kt++){
    uint2 pk;
    pk.x = (unsigned)f2bf(acc[kt][0]*inv) | ((unsigned)f2bf(acc[kt][1]*inv) << 16);
    pk.y = (unsigned)f2bf(acc[kt][2]*inv) | ((unsigned)f2bf(acc[kt][3]*inv) << 16);
    *(uint2*)((char*)&Ps[w][0][0] + q15*528 + (kt<<5) + (g<<3)) = pk;
  }

  // PV: out[q][hd] = sum_k P[q][k] * V[k][hd]; V from fragment layout
  #pragma unroll
  for (int ht = 0; ht < 4; ht++){
    float4v oa = {0.f,0.f,0.f,0.f};
    #pragma unroll
    for (int kb = 0; kb < 8; kb++){
      short8 pf = *(const short8*)((char*)&Ps[w][0][0] + q15*528 + (kb<<6) + (g<<4));
      short8 vf = *(const short8*)(vt + base + (size_t)((((kb<<6) + (ht<<4) + q15)) << 5) + (g<<3));
      oa = MFMA16(pf, vf, oa);
    }
    #pragma unroll
    for (int r = 0; r < 4; r++){
      int qo = qbase + (g<<2) + r;
      ao[((size_t)(b*256 + qo) << 9) + (h<<6) + (ht<<4) + q15] = f2bf(oa[r]);
    }
  }
}

// ---------------------------------------------------------------------------
extern "C" void kernel_launch(void* const* d_in, const int* in_sizes, int n_in,
                              void* d_out, int out_size, void* d_ws, size_t ws_size,
                              hipStream_t stream)
{
  const float* x     = (const float*)d_in[0];
  const float* Wq    = (const float*)d_in[1];
  const float* bq    = (const float*)d_in[2];
  const float* Wk    = (const float*)d_in[3];
  const float* bk    = (const float*)d_in[4];
  const float* Wv    = (const float*)d_in[5];
  const float* bv    = (const float*)d_in[6];
  const float* Wo    = (const float*)d_in[7];
  const float* bo    = (const float*)d_in[8];
  const float* prior = (const float*)d_in[9];
  const float* fimp  = (const float*)d_in[10];
  const float* W1    = (const float*)d_in[11];
  const float* b1    = (const float*)d_in[12];
  const float* W2    = (const float*)d_in[13];
  const float* b2    = (const float*)d_in[14];

  char* ws = (char*)d_ws;
  ushort* xhi  = (ushort*)(ws + 0);            // 16.78 MB
  ushort* xlo  = (ushort*)(ws + 16777216);
  ushort* qhi  = (ushort*)(ws + 33554432);
  ushort* qlo  = (ushort*)(ws + 50331648);
  ushort* khi  = (ushort*)(ws + 67108864);
  ushort* klo  = (ushort*)(ws + 83886080);
  ushort* vt   = (ushort*)(ws + 100663296);    // V in MFMA fragment layout
  ushort* Wthi = (ushort*)(ws + 117440512);
  ushort* Wtlo = (ushort*)(ws + 119013376);
  ushort* Wot  = (ushort*)(ws + 120061952);
  float*  fb   = (float*) (ws + 120586240);
  float*  comb = (float*) (ws + 120592384);
  float*  pvc  = (float*) (ws + 120854528);
  float*  pe   = (float*) (ws + 120854784);
  ushort* ao   = xhi;   // alias: xhi dead after the projection GEMMs

  cvt_x_k <<<4096, 256, 0, stream>>>(x, xhi, xlo);
  cvt_w_k <<<2049, 256, 0, stream>>>(Wq, Wk, Wv, Wo, bq, bk, bv, Wthi, Wtlo, Wot, fb);
  prior_k <<<256, 256, 0, stream>>>(prior, fimp, pe);
  pv_mean_k<<<64, 256, 0, stream>>>(x, comb);
  pv_mlp_k <<<64, 256, 0, stream>>>(comb, W1, b1, W2, b2, pvc);
  gemm_qk <<<dim3(8,128), 256, 0, stream>>>(xhi, xlo, Wthi, Wtlo, fb, qhi, qlo, khi, klo);
  gemm_pl<0><<<dim3(4,128), 256, 0, stream>>>(xhi, Wthi + (size_t)1024*512, fb + 1024, vt);
  attn_k  <<<2048, 256, 0, stream>>>(qhi, qlo, khi, klo, vt, pe, pvc, ao);
  gemm_pl<1><<<dim3(4,128), 256, 0, stream>>>(ao, Wot, bo, d_out);

  (void)in_sizes; (void)n_in; (void)out_size; (void)ws_size;
}